// Round 6
// baseline (354.092 us; speedup 1.0000x reference)
//
#include <hip/hip_runtime.h>

#define N_ROWS 32768   // 32 * 32 * 32  (B*H*W)
#define K_CODES 1024
#define CDIM 256

typedef _Float16 half8 __attribute__((ext_vector_type(8)));
typedef _Float16 half4 __attribute__((ext_vector_type(4)));
typedef float floatx16 __attribute__((ext_vector_type(16)));
typedef unsigned long long ull;

// fast-path workspace layout (bytes)
// zh/zl packed q-major: [32 ccq][32768 n][8 halves]  (16 MB each)
//   ccq = (c/32)*4 + (c%32)/8  -> granule of 8 halves per (ccq, n)
// cbh/cbl packed: [32 ccq][1024 k][8]                (512 KB each)
#define WS_ZH   0ull
#define WS_ZL   16777216ull
#define WS_CBH  33554432ull
#define WS_CBL  34078720ull
#define WS_CBN  34603008ull
#define WS_PART 34607104ull
#define WS_IDX  36704256ull
#define WS_NEED 36835328ull

__device__ __forceinline__ void g2lds16(const void* g, void* l) {
    __builtin_amdgcn_global_load_lds(
        (const __attribute__((address_space(1))) void*)g,
        (__attribute__((address_space(3))) void*)l, 16, 0, 0);
}

// ================= fast path (fp16 hi/lo split + 32x32 MFMA) =================

// codebook prep: scale by 32, split fp16 hi/lo into q-major layout, norms
__global__ __launch_bounds__(64) void cb_prep(const float* __restrict__ cb,
                                              _Float16* __restrict__ cbh,
                                              _Float16* __restrict__ cbl,
                                              float* __restrict__ cbn) {
    int k = blockIdx.x;
    int lane = threadIdx.x;          // c = lane*4
    float4 v = reinterpret_cast<const float4*>(cb + k * CDIM)[lane];
    float s0 = v.x * 32.f, s1 = v.y * 32.f, s2 = v.z * 32.f, s3 = v.w * 32.f;
    half4 hv, lv;
    hv[0] = (_Float16)s0; lv[0] = (_Float16)(s0 - (float)hv[0]);
    hv[1] = (_Float16)s1; lv[1] = (_Float16)(s1 - (float)hv[1]);
    hv[2] = (_Float16)s2; lv[2] = (_Float16)(s2 - (float)hv[2]);
    hv[3] = (_Float16)s3; lv[3] = (_Float16)(s3 - (float)hv[3]);
    int cc = lane >> 3;              // (lane*4)>>5
    int q  = (lane >> 1) & 3;        // ((lane*4)>>3)&3
    size_t off = (size_t)((cc * 4 + q) * K_CODES + k) * 8 + (lane & 1) * 4;
    *reinterpret_cast<half4*>(&cbh[off]) = hv;
    *reinterpret_cast<half4*>(&cbl[off]) = lv;
    float s = s0 * s0 + s1 * s1 + s2 * s2 + s3 * s3;
    #pragma unroll
    for (int off2 = 32; off2 > 0; off2 >>= 1) s += __shfl_down(s, off2);
    if (lane == 0) cbn[k] = s;
}

// z prep: (B,C,H,W) -> q-major [ccq][n][8], scale by 32, split hi/lo.
// Store phase: lane = hw -> consecutive n -> contiguous 16B/lane (1KB/wave).
__global__ __launch_bounds__(256) void z_prep(const float* __restrict__ z,
                                              _Float16* __restrict__ zh,
                                              _Float16* __restrict__ zl) {
    __shared__ float t[64][68];
    int hwt = blockIdx.x & 15;
    int ct  = (blockIdx.x >> 4) & 3;
    int bb  = blockIdx.x >> 6;
    int tid = threadIdx.x;
    #pragma unroll
    for (int p = 0; p < 4; p++) {
        int e = p * 256 + tid;
        int c = e >> 4, h4 = e & 15;
        float4 v = *reinterpret_cast<const float4*>(
            &z[((bb * 256 + ct * 64 + c) << 10) + hwt * 64 + h4 * 4]);
        *reinterpret_cast<float4*>(&t[c][h4 * 4]) = v;
    }
    __syncthreads();
    int hw = tid & 63, g8 = tid >> 6;        // g8: 0..3
    int n = bb * 1024 + hwt * 64 + hw;
    #pragma unroll
    for (int p = 0; p < 2; p++) {
        int o = g8 * 2 + p;                  // channel octet 0..7 within 64-c tile
        int cg = ct * 64 + o * 8;
        int cc = cg >> 5, q = (cg >> 3) & 3;
        half8 hv, lv;
        #pragma unroll
        for (int j = 0; j < 8; j++) {
            float s = t[o * 8 + j][hw] * 32.f;
            _Float16 h = (_Float16)s;
            hv[j] = h;
            lv[j] = (_Float16)(s - (float)h);
        }
        size_t off = (size_t)((cc * 4 + q) * N_ROWS + n) * 8;
        *reinterpret_cast<half8*>(&zh[off]) = hv;
        *reinterpret_cast<half8*>(&zl[off]) = lv;
    }
}

// GEMM+argmin: block 256 rows x 128 codes, 4 waves (128x64 each: 4x2 of 32x32),
// c-chunks of 32, 32x32x16 f16 MFMA, shared fp32 acc for 3 hi/lo terms.
// Staging: q-major global layout -> each wave loads 1KB contiguous (full lines).
// d_scaled(n,k) = ||32e||^2 - 2*(32z).(32e) = 1024*d_true (argmin invariant)
__global__ __launch_bounds__(256, 3) void vq_mfma32(
    const _Float16* __restrict__ zh, const _Float16* __restrict__ zl,
    const _Float16* __restrict__ cbh, const _Float16* __restrict__ cbl,
    const float* __restrict__ cbn, ull* __restrict__ partial) {

    // LDS granule-major: A granule ga=(q*256+row), B granule gb=(q*128+col)
    __shared__ _Float16 AhL[8192], AlL[8192];   // 16 KB each
    __shared__ _Float16 BhL[4096], BlL[4096];   // 8 KB each  -> 48 KB total

    const int tid = threadIdx.x;
    const int lane = tid & 63, wave = tid >> 6;
    const int wm = wave & 1, wn = wave >> 1;   // wave: rows wm*128, codes wn*64
    const int fm = lane & 31, fq = lane >> 5;  // row/col in 32-tile, k-octet
    // swizzle: codeTile slow (bid>>7); rowTile pinned per-XCD (bid%8 = XCD)
    const int codeTile = blockIdx.x >> 7;
    const int g = blockIdx.x & 127;
    const int rowTile = (g & 7) * 16 + (g >> 3);
    const int rowBase = rowTile * 256, codeBase = codeTile * 128;

    floatx16 acc[8];   // [i*2+j]: row sub-tile i (0..3 -> +i*32), code sub-tile j
    #pragma unroll
    for (int i = 0; i < 8; i++) acc[i] = (floatx16)0.f;

    for (int kc = 0; kc < CDIM; kc += 32) {
        const int cc = kc >> 5;
        #pragma unroll
        for (int i = 0; i < 4; i++) {           // A: 1024 granules per buffer
            int G = i * 256 + tid;
            int q = G >> 8, r = G & 255;
            size_t so = (size_t)((cc * 4 + q) * N_ROWS + rowBase + r) * 8;
            g2lds16(zh + so, &AhL[G * 8]);
            g2lds16(zl + so, &AlL[G * 8]);
        }
        #pragma unroll
        for (int i = 0; i < 2; i++) {           // B: 512 granules per buffer
            int G = i * 256 + tid;
            int q = G >> 7, c2 = G & 127;
            size_t so = (size_t)((cc * 4 + q) * K_CODES + codeBase + c2) * 8;
            g2lds16(cbh + so, &BhL[G * 8]);
            g2lds16(cbl + so, &BlL[G * 8]);
        }
        __syncthreads();
        #pragma unroll
        for (int s = 0; s < 2; s++) {           // two k16 steps per chunk
            int q = s * 2 + fq;
            half8 ah[4], al[4], bh[2], bl[2];
            #pragma unroll
            for (int i = 0; i < 4; i++) {
                int ga = q * 256 + wm * 128 + i * 32 + fm;
                ah[i] = *reinterpret_cast<const half8*>(&AhL[ga * 8]);
                al[i] = *reinterpret_cast<const half8*>(&AlL[ga * 8]);
            }
            #pragma unroll
            for (int j = 0; j < 2; j++) {
                int gb = q * 128 + wn * 64 + j * 32 + fm;
                bh[j] = *reinterpret_cast<const half8*>(&BhL[gb * 8]);
                bl[j] = *reinterpret_cast<const half8*>(&BlL[gb * 8]);
            }
            #pragma unroll
            for (int i = 0; i < 4; i++)
                #pragma unroll
                for (int j = 0; j < 2; j++) {
                    acc[i*2+j] = __builtin_amdgcn_mfma_f32_32x32x16_f16(ah[i], bh[j], acc[i*2+j], 0, 0, 0);
                    acc[i*2+j] = __builtin_amdgcn_mfma_f32_32x32x16_f16(al[i], bh[j], acc[i*2+j], 0, 0, 0);
                    acc[i*2+j] = __builtin_amdgcn_mfma_f32_32x32x16_f16(ah[i], bl[j], acc[i*2+j], 0, 0, 0);
                }
        }
        __syncthreads();
    }

    // epilogue: d = cbn - 2*acc; argmin per row.
    // 32x32 C/D: col = lane&31, row = (reg&3) + 8*(reg>>2) + 4*(lane>>5)
    // reduction arrays alias AhL (main loop done; all frag reads barriered)
    float (*rvv)[2] = reinterpret_cast<float(*)[2]>(&AhL[0]);      // 2 KB
    int   (*rcc)[2] = reinterpret_cast<int(*)[2]>(&AhL[1024]);     // 2 KB

    float cbnv[2];
    #pragma unroll
    for (int j = 0; j < 2; j++) cbnv[j] = cbn[codeBase + wn * 64 + j * 32 + fm];

    #pragma unroll
    for (int i = 0; i < 4; i++)
        #pragma unroll
        for (int r = 0; r < 16; r++) {
            float best = 3.4e38f; int bcode = 0x7fffffff;
            #pragma unroll
            for (int j = 0; j < 2; j++) {   // ascending code: strict < = first-min
                float d = fmaf(-2.f, acc[i*2+j][r], cbnv[j]);
                int code = codeBase + wn * 64 + j * 32 + fm;
                if (d < best) { best = d; bcode = code; }
            }
            // butterfly over the 32 lanes of this k-half (lex (val, code))
            #pragma unroll
            for (int m = 1; m < 32; m <<= 1) {
                float ov = __shfl_xor(best, m, 64);
                int   oc = __shfl_xor(bcode, m, 64);
                if (ov < best || (ov == best && oc < bcode)) { best = ov; bcode = oc; }
            }
            if (fm == 0) {
                int row = wm * 128 + i * 32 + (r & 3) + 8 * (r >> 2) + 4 * fq;
                rvv[row][wn] = best;
                rcc[row][wn] = bcode;
            }
        }
    __syncthreads();
    {
        float v0 = rvv[tid][0]; int c0 = rcc[tid][0];
        float v1 = rvv[tid][1]; int c1 = rcc[tid][1];
        if (v1 < v0 || (v1 == v0 && c1 < c0)) { v0 = v1; c0 = c1; }
        unsigned u = __float_as_uint(v0);
        u = (u & 0x80000000u) ? ~u : (u | 0x80000000u);   // monotone map
        partial[(size_t)(rowBase + tid) * 8 + codeTile] =
            ((ull)u << 32) | (unsigned)c0;
    }
}

// one-hot fill + cross-tile argmin finalize (one block per row)
__global__ __launch_bounds__(256) void onehot_fin(const ull* __restrict__ partial,
                                                  int* __restrict__ idx,
                                                  float* __restrict__ out) {
    int row = blockIdx.x;
    __shared__ int sid;
    if (threadIdx.x < 64) {
        ull v = (threadIdx.x < 8) ? partial[(size_t)row * 8 + threadIdx.x]
                                  : ~0ull;
        #pragma unroll
        for (int m = 1; m < 8; m <<= 1) {
            ull o = __shfl_xor(v, m, 64);
            if (o < v) v = o;
        }
        if (threadIdx.x == 0) {
            int id = (int)(v & 0xffffffffu);
            sid = id;
            idx[row] = id;
        }
    }
    __syncthreads();
    int id = sid;
    int k4 = threadIdx.x << 2;
    float4 v4;
    v4.x = (k4     == id) ? 1.f : 0.f;
    v4.y = (k4 + 1 == id) ? 1.f : 0.f;
    v4.z = (k4 + 2 == id) ? 1.f : 0.f;
    v4.w = (k4 + 3 == id) ? 1.f : 0.f;
    reinterpret_cast<float4*>(out)[(size_t)row * 256 + threadIdx.x] = v4;
}

// ---------------- z_quantized gather, (B,C,H,W) layout ----------------
__global__ __launch_bounds__(256) void zq_fill(const int* __restrict__ idx,
                                               const float* __restrict__ cb,
                                               float* __restrict__ out) {
    int i  = blockIdx.x * 256 + threadIdx.x;
    int hw = i & 1023;
    int c  = (i >> 10) & 255;
    int b  = i >> 18;
    int n  = (b << 10) | hw;
    out[i] = cb[idx[n] * CDIM + c];
}

// ================= fallback path (round-2 fp32 VALU, known-good) =================

__global__ __launch_bounds__(64) void cb_norms(const float* __restrict__ cb,
                                               float* __restrict__ cbn) {
    int k = blockIdx.x;
    int lane = threadIdx.x;
    float4 v = reinterpret_cast<const float4*>(cb + k * CDIM)[lane];
    float s = v.x * v.x + v.y * v.y + v.z * v.z + v.w * v.w;
    #pragma unroll
    for (int off = 32; off > 0; off >>= 1) s += __shfl_down(s, off);
    if (lane == 0) cbn[k] = s;
}

__global__ __launch_bounds__(256) void cb_transpose(const float* __restrict__ cb,
                                                    float* __restrict__ cbt) {
    __shared__ float t[32][33];
    int k0 = (blockIdx.x & 31) * 32;
    int c0 = (blockIdx.x >> 5) * 32;
    int lane = threadIdx.x & 31;
    int row = threadIdx.x >> 5;
    #pragma unroll
    for (int s = 0; s < 4; s++) {
        int r = row + s * 8;
        t[r][lane] = cb[(k0 + r) * CDIM + c0 + lane];
    }
    __syncthreads();
    #pragma unroll
    for (int s = 0; s < 4; s++) {
        int r = row + s * 8;
        cbt[(c0 + r) * K_CODES + k0 + lane] = t[lane][r];
    }
}

__global__ __launch_bounds__(512, 2) void vq_argmin(const float* __restrict__ z,
                                                    const float* __restrict__ cbt,
                                                    const float* __restrict__ cbn,
                                                    int* __restrict__ idx_out) {
    __shared__ float As[64][128];
    __shared__ float Bs[64][256];

    const int tid = threadIdx.x;
    const int tx = tid & 31;
    const int ty = tid >> 5;
    const int rowBase = blockIdx.x * 128;
    const int bb = rowBase >> 10;
    const int hwBase = rowBase & 1023;

    float minv[8];
    int   mini[8];
    #pragma unroll
    for (int i = 0; i < 8; i++) { minv[i] = 3.4e38f; mini[i] = 0; }

    for (int kt = 0; kt < K_CODES; kt += 256) {
        float acc[2][2][4][4];
        #pragma unroll
        for (int a = 0; a < 2; a++)
            #pragma unroll
            for (int b = 0; b < 2; b++)
                #pragma unroll
                for (int i = 0; i < 4; i++)
                    #pragma unroll
                    for (int j = 0; j < 4; j++) acc[a][b][i][j] = 0.f;

        for (int ccb = 0; ccb < CDIM; ccb += 64) {
            #pragma unroll
            for (int l = 0; l < 4; l++) {
                int f = tid + l * 512;
                int r4 = f & 31, c = f >> 5;
                float4 v = *reinterpret_cast<const float4*>(
                    &z[((bb * 256 + ccb + c) << 10) + hwBase + r4 * 4]);
                *reinterpret_cast<float4*>(&As[c][r4 * 4]) = v;
            }
            #pragma unroll
            for (int l = 0; l < 8; l++) {
                int f = tid + l * 512;
                int k4 = f & 63, c = f >> 6;
                float4 v = *reinterpret_cast<const float4*>(
                    &cbt[(ccb + c) * K_CODES + kt + k4 * 4]);
                *reinterpret_cast<float4*>(&Bs[c][k4 * 4]) = v;
            }
            __syncthreads();
            #pragma unroll 4
            for (int c = 0; c < 64; c++) {
                float4 a0 = *reinterpret_cast<const float4*>(&As[c][ty * 4]);
                float4 a1 = *reinterpret_cast<const float4*>(&As[c][64 + ty * 4]);
                float4 b0 = *reinterpret_cast<const float4*>(&Bs[c][tx * 4]);
                float4 b1 = *reinterpret_cast<const float4*>(&Bs[c][128 + tx * 4]);
                float av[2][4] = {{a0.x, a0.y, a0.z, a0.w}, {a1.x, a1.y, a1.z, a1.w}};
                float bw[2][4] = {{b0.x, b0.y, b0.z, b0.w}, {b1.x, b1.y, b1.z, b1.w}};
                #pragma unroll
                for (int ri = 0; ri < 2; ri++)
                    #pragma unroll
                    for (int i = 0; i < 4; i++)
                        #pragma unroll
                        for (int ci = 0; ci < 2; ci++)
                            #pragma unroll
                            for (int j = 0; j < 4; j++)
                                acc[ri][ci][i][j] =
                                    fmaf(av[ri][i], bw[ci][j], acc[ri][ci][i][j]);
            }
            __syncthreads();
        }
        #pragma unroll
        for (int ci = 0; ci < 2; ci++)
            #pragma unroll
            for (int j = 0; j < 4; j++) {
                int code = kt + ci * 128 + tx * 4 + j;
                float nrm = cbn[code];
                #pragma unroll
                for (int ri = 0; ri < 2; ri++)
                    #pragma unroll
                    for (int i = 0; i < 4; i++) {
                        float d = fmaf(-2.f, acc[ri][ci][i][j], nrm);
                        int r = ri * 4 + i;
                        if (d < minv[r]) { minv[r] = d; mini[r] = code; }
                    }
            }
    }

    __syncthreads();
    float (*rv)[32] = reinterpret_cast<float(*)[32]>(&As[0][0]);
    int   (*rix)[32] = reinterpret_cast<int(*)[32]>(&As[32][0]);
    #pragma unroll
    for (int ri = 0; ri < 2; ri++)
        #pragma unroll
        for (int i = 0; i < 4; i++) {
            int row = ri * 64 + ty * 4 + i;
            rv[row][tx] = minv[ri * 4 + i];
            rix[row][tx] = mini[ri * 4 + i];
        }
    __syncthreads();
    if (tid < 128) {
        float bvv = rv[tid][0]; int bii = rix[tid][0];
        #pragma unroll
        for (int t = 1; t < 32; t++) {
            float v = rv[tid][t]; int ii = rix[tid][t];
            if (v < bvv || (v == bvv && ii < bii)) { bvv = v; bii = ii; }
        }
        idx_out[rowBase + tid] = bii;
    }
}

__global__ __launch_bounds__(256) void onehot_fill(const int* __restrict__ idx,
                                                   float* __restrict__ out) {
    int i = blockIdx.x * 256 + threadIdx.x;
    int n  = i >> 8;
    int k4 = (i & 255) << 2;
    int id = idx[n];
    float4 v;
    v.x = (k4     == id) ? 1.f : 0.f;
    v.y = (k4 + 1 == id) ? 1.f : 0.f;
    v.z = (k4 + 2 == id) ? 1.f : 0.f;
    v.w = (k4 + 3 == id) ? 1.f : 0.f;
    reinterpret_cast<float4*>(out)[i] = v;
}

extern "C" void kernel_launch(void* const* d_in, const int* in_sizes, int n_in,
                              void* d_out, int out_size, void* d_ws, size_t ws_size,
                              hipStream_t stream) {
    const float* z  = (const float*)d_in[0];
    const float* cb = (const float*)d_in[1];
    float* out0 = (float*)d_out;
    float* out1 = out0 + (size_t)N_ROWS * K_CODES;

    if (ws_size >= WS_NEED) {
        _Float16* zh  = (_Float16*)((char*)d_ws + WS_ZH);
        _Float16* zl  = (_Float16*)((char*)d_ws + WS_ZL);
        _Float16* cbh = (_Float16*)((char*)d_ws + WS_CBH);
        _Float16* cbl = (_Float16*)((char*)d_ws + WS_CBL);
        float* cbn = (float*)((char*)d_ws + WS_CBN);
        ull* part = (ull*)((char*)d_ws + WS_PART);
        int* idx = (int*)((char*)d_ws + WS_IDX);

        cb_prep<<<K_CODES, 64, 0, stream>>>(cb, cbh, cbl, cbn);
        z_prep<<<2048, 256, 0, stream>>>(z, zh, zl);
        vq_mfma32<<<1024, 256, 0, stream>>>(zh, zl, cbh, cbl, cbn, part);
        onehot_fin<<<N_ROWS, 256, 0, stream>>>(part, idx, out0);
        zq_fill<<<(N_ROWS * CDIM) / 256, 256, 0, stream>>>(idx, cb, out1);
    } else {
        float* cbn = (float*)d_ws;
        int*   idx = (int*)((char*)d_ws + 4096);
        float* cbt = (float*)((char*)d_ws + 4096 + 131072);

        cb_norms<<<K_CODES, 64, 0, stream>>>(cb, cbn);
        cb_transpose<<<256, 256, 0, stream>>>(cb, cbt);
        vq_argmin<<<N_ROWS / 128, 512, 0, stream>>>(z, cbt, cbn, idx);
        onehot_fill<<<(N_ROWS * K_CODES / 4) / 256, 256, 0, stream>>>(idx, out0);
        zq_fill<<<(N_ROWS * CDIM) / 256, 256, 0, stream>>>(idx, cb, out1);
    }
}

// Round 7
// 303.555 us; speedup vs baseline: 1.1665x; 1.1665x over previous
//
#include <hip/hip_runtime.h>

#define N_ROWS 32768   // 32 * 32 * 32  (B*H*W)
#define K_CODES 1024
#define CDIM 256

typedef _Float16 half8 __attribute__((ext_vector_type(8)));
typedef _Float16 half4 __attribute__((ext_vector_type(4)));
typedef float floatx16 __attribute__((ext_vector_type(16)));
typedef unsigned long long ull;

// fast-path workspace layout (bytes)
// zh/zl packed q-major: [32 ccq][32768 n][8 halves]  (16 MB each)
//   ccq = (c/32)*4 + (c%32)/8  -> granule of 8 halves per (ccq, n)
// cbh/cbl packed: [32 ccq][1024 k][8]                (512 KB each)
#define WS_ZH   0ull
#define WS_ZL   16777216ull
#define WS_CBH  33554432ull
#define WS_CBL  34078720ull
#define WS_CBN  34603008ull
#define WS_PART 34607104ull
#define WS_IDX  36704256ull
#define WS_NEED 36835328ull

__device__ __forceinline__ void g2lds16(const void* g, void* l) {
    __builtin_amdgcn_global_load_lds(
        (const __attribute__((address_space(1))) void*)g,
        (__attribute__((address_space(3))) void*)l, 16, 0, 0);
}

// ================= fast path (fp16 hi/lo split + 32x32 MFMA) =================

// codebook prep: scale by 32, split fp16 hi/lo into q-major layout, norms
__global__ __launch_bounds__(64) void cb_prep(const float* __restrict__ cb,
                                              _Float16* __restrict__ cbh,
                                              _Float16* __restrict__ cbl,
                                              float* __restrict__ cbn) {
    int k = blockIdx.x;
    int lane = threadIdx.x;          // c = lane*4
    float4 v = reinterpret_cast<const float4*>(cb + k * CDIM)[lane];
    float s0 = v.x * 32.f, s1 = v.y * 32.f, s2 = v.z * 32.f, s3 = v.w * 32.f;
    half4 hv, lv;
    hv[0] = (_Float16)s0; lv[0] = (_Float16)(s0 - (float)hv[0]);
    hv[1] = (_Float16)s1; lv[1] = (_Float16)(s1 - (float)hv[1]);
    hv[2] = (_Float16)s2; lv[2] = (_Float16)(s2 - (float)hv[2]);
    hv[3] = (_Float16)s3; lv[3] = (_Float16)(s3 - (float)hv[3]);
    int cc = lane >> 3;              // (lane*4)>>5
    int q  = (lane >> 1) & 3;        // ((lane*4)>>3)&3
    size_t off = (size_t)((cc * 4 + q) * K_CODES + k) * 8 + (lane & 1) * 4;
    *reinterpret_cast<half4*>(&cbh[off]) = hv;
    *reinterpret_cast<half4*>(&cbl[off]) = lv;
    float s = s0 * s0 + s1 * s1 + s2 * s2 + s3 * s3;
    #pragma unroll
    for (int off2 = 32; off2 > 0; off2 >>= 1) s += __shfl_down(s, off2);
    if (lane == 0) cbn[k] = s;
}

// z prep: (B,C,H,W) -> q-major [ccq][n][8], scale by 32, split hi/lo.
// Store phase: lane = hw -> consecutive n -> contiguous 16B/lane (1KB/wave).
__global__ __launch_bounds__(256) void z_prep(const float* __restrict__ z,
                                              _Float16* __restrict__ zh,
                                              _Float16* __restrict__ zl) {
    __shared__ float t[64][68];
    int hwt = blockIdx.x & 15;
    int ct  = (blockIdx.x >> 4) & 3;
    int bb  = blockIdx.x >> 6;
    int tid = threadIdx.x;
    #pragma unroll
    for (int p = 0; p < 4; p++) {
        int e = p * 256 + tid;
        int c = e >> 4, h4 = e & 15;
        float4 v = *reinterpret_cast<const float4*>(
            &z[((bb * 256 + ct * 64 + c) << 10) + hwt * 64 + h4 * 4]);
        *reinterpret_cast<float4*>(&t[c][h4 * 4]) = v;
    }
    __syncthreads();
    int hw = tid & 63, g8 = tid >> 6;        // g8: 0..3
    int n = bb * 1024 + hwt * 64 + hw;
    #pragma unroll
    for (int p = 0; p < 2; p++) {
        int o = g8 * 2 + p;                  // channel octet 0..7 within 64-c tile
        int cg = ct * 64 + o * 8;
        int cc = cg >> 5, q = (cg >> 3) & 3;
        half8 hv, lv;
        #pragma unroll
        for (int j = 0; j < 8; j++) {
            float s = t[o * 8 + j][hw] * 32.f;
            _Float16 h = (_Float16)s;
            hv[j] = h;
            lv[j] = (_Float16)(s - (float)h);
        }
        size_t off = (size_t)((cc * 4 + q) * N_ROWS + n) * 8;
        *reinterpret_cast<half8*>(&zh[off]) = hv;
        *reinterpret_cast<half8*>(&zl[off]) = lv;
    }
}

// GEMM+argmin: block 128 rows x 128 codes (round-4 shape: small tile, deep
// occupancy wins over FLOP/byte balance), 4 waves (64x64 each: 2x2 of 32x32),
// c-chunks of 32, 32x32x16 f16 MFMA, shared fp32 acc for 3 hi/lo terms.
// Staging: q-major global layout -> each wave loads 1KB contiguous lines.
// 32KB LDS + launch_bounds(256,4): 4 blocks/CU -> 4 waves/SIMD cover the
// vmcnt(0) barrier drain (round-6 lesson: 2-3 waves/SIMD idles everything).
// d_scaled(n,k) = ||32e||^2 - 2*(32z).(32e) = 1024*d_true (argmin invariant)
__global__ __launch_bounds__(256, 4) void vq_mfma32(
    const _Float16* __restrict__ zh, const _Float16* __restrict__ zl,
    const _Float16* __restrict__ cbh, const _Float16* __restrict__ cbl,
    const float* __restrict__ cbn, ull* __restrict__ partial) {

    // LDS granule-major: A granule ga=(q*128+row), B granule gb=(q*128+col)
    __shared__ _Float16 AhL[4096], AlL[4096];   // 8 KB each
    __shared__ _Float16 BhL[4096], BlL[4096];   // 8 KB each  -> 32 KB total

    const int tid = threadIdx.x;
    const int lane = tid & 63, wave = tid >> 6;
    const int wm = wave & 1, wn = wave >> 1;   // wave: rows wm*64, codes wn*64
    const int fm = lane & 31, fq = lane >> 5;  // row/col in 32-tile, k-octet
    // swizzle: codeTile slow (bid>>8); rowTile pinned per-XCD (bid%8 = XCD)
    const int codeTile = blockIdx.x >> 8;
    const int g = blockIdx.x & 255;
    const int rowTile = (g & 7) * 32 + (g >> 3);
    const int rowBase = rowTile * 128, codeBase = codeTile * 128;

    floatx16 acc[4];   // [i*2+j]: row sub-tile i (0/1 -> +i*32), code sub-tile j
    #pragma unroll
    for (int i = 0; i < 4; i++) acc[i] = (floatx16)0.f;

    for (int kc = 0; kc < CDIM; kc += 32) {
        const int cc = kc >> 5;
        #pragma unroll
        for (int i = 0; i < 2; i++) {           // A: 512 granules per buffer
            int G = i * 256 + tid;
            int q = G >> 7, r = G & 127;
            size_t so = (size_t)((cc * 4 + q) * N_ROWS + rowBase + r) * 8;
            g2lds16(zh + so, &AhL[G * 8]);
            g2lds16(zl + so, &AlL[G * 8]);
        }
        #pragma unroll
        for (int i = 0; i < 2; i++) {           // B: 512 granules per buffer
            int G = i * 256 + tid;
            int q = G >> 7, c2 = G & 127;
            size_t so = (size_t)((cc * 4 + q) * K_CODES + codeBase + c2) * 8;
            g2lds16(cbh + so, &BhL[G * 8]);
            g2lds16(cbl + so, &BlL[G * 8]);
        }
        __syncthreads();
        #pragma unroll
        for (int s = 0; s < 2; s++) {           // two k16 steps per chunk
            int q = s * 2 + fq;
            half8 ah[2], al[2], bh[2], bl[2];
            #pragma unroll
            for (int i = 0; i < 2; i++) {
                int ga = q * 128 + wm * 64 + i * 32 + fm;
                ah[i] = *reinterpret_cast<const half8*>(&AhL[ga * 8]);
                al[i] = *reinterpret_cast<const half8*>(&AlL[ga * 8]);
            }
            #pragma unroll
            for (int j = 0; j < 2; j++) {
                int gb = q * 128 + wn * 64 + j * 32 + fm;
                bh[j] = *reinterpret_cast<const half8*>(&BhL[gb * 8]);
                bl[j] = *reinterpret_cast<const half8*>(&BlL[gb * 8]);
            }
            #pragma unroll
            for (int i = 0; i < 2; i++)
                #pragma unroll
                for (int j = 0; j < 2; j++) {
                    acc[i*2+j] = __builtin_amdgcn_mfma_f32_32x32x16_f16(ah[i], bh[j], acc[i*2+j], 0, 0, 0);
                    acc[i*2+j] = __builtin_amdgcn_mfma_f32_32x32x16_f16(al[i], bh[j], acc[i*2+j], 0, 0, 0);
                    acc[i*2+j] = __builtin_amdgcn_mfma_f32_32x32x16_f16(ah[i], bl[j], acc[i*2+j], 0, 0, 0);
                }
        }
        __syncthreads();
    }

    // epilogue: d = cbn - 2*acc; argmin per row.
    // 32x32 C/D: col = lane&31, row = (reg&3) + 8*(reg>>2) + 4*(lane>>5)
    // reduction arrays alias AhL (main loop done; last frag reads barriered)
    float (*rvv)[2] = reinterpret_cast<float(*)[2]>(&AhL[0]);      // 1 KB
    int   (*rcc)[2] = reinterpret_cast<int(*)[2]>(&AhL[1024]);     // 1 KB

    float cbnv[2];
    #pragma unroll
    for (int j = 0; j < 2; j++) cbnv[j] = cbn[codeBase + wn * 64 + j * 32 + fm];

    #pragma unroll
    for (int i = 0; i < 2; i++)
        #pragma unroll
        for (int r = 0; r < 16; r++) {
            float best = 3.4e38f; int bcode = 0x7fffffff;
            #pragma unroll
            for (int j = 0; j < 2; j++) {   // ascending code: strict < = first-min
                float d = fmaf(-2.f, acc[i*2+j][r], cbnv[j]);
                int code = codeBase + wn * 64 + j * 32 + fm;
                if (d < best) { best = d; bcode = code; }
            }
            // butterfly over the 32 lanes of this k-half (lex (val, code))
            #pragma unroll
            for (int m = 1; m < 32; m <<= 1) {
                float ov = __shfl_xor(best, m, 64);
                int   oc = __shfl_xor(bcode, m, 64);
                if (ov < best || (ov == best && oc < bcode)) { best = ov; bcode = oc; }
            }
            if (fm == 0) {
                int row = wm * 64 + i * 32 + (r & 3) + 8 * (r >> 2) + 4 * fq;
                rvv[row][wn] = best;
                rcc[row][wn] = bcode;
            }
        }
    __syncthreads();
    if (tid < 128) {
        float v0 = rvv[tid][0]; int c0 = rcc[tid][0];
        float v1 = rvv[tid][1]; int c1 = rcc[tid][1];
        if (v1 < v0 || (v1 == v0 && c1 < c0)) { v0 = v1; c0 = c1; }
        unsigned u = __float_as_uint(v0);
        u = (u & 0x80000000u) ? ~u : (u | 0x80000000u);   // monotone map
        partial[(size_t)(rowBase + tid) * 8 + codeTile] =
            ((ull)u << 32) | (unsigned)c0;
    }
}

// one-hot fill + cross-tile argmin finalize (one block per row)
__global__ __launch_bounds__(256) void onehot_fin(const ull* __restrict__ partial,
                                                  int* __restrict__ idx,
                                                  float* __restrict__ out) {
    int row = blockIdx.x;
    __shared__ int sid;
    if (threadIdx.x < 64) {
        ull v = (threadIdx.x < 8) ? partial[(size_t)row * 8 + threadIdx.x]
                                  : ~0ull;
        #pragma unroll
        for (int m = 1; m < 8; m <<= 1) {
            ull o = __shfl_xor(v, m, 64);
            if (o < v) v = o;
        }
        if (threadIdx.x == 0) {
            int id = (int)(v & 0xffffffffu);
            sid = id;
            idx[row] = id;
        }
    }
    __syncthreads();
    int id = sid;
    int k4 = threadIdx.x << 2;
    float4 v4;
    v4.x = (k4     == id) ? 1.f : 0.f;
    v4.y = (k4 + 1 == id) ? 1.f : 0.f;
    v4.z = (k4 + 2 == id) ? 1.f : 0.f;
    v4.w = (k4 + 3 == id) ? 1.f : 0.f;
    reinterpret_cast<float4*>(out)[(size_t)row * 256 + threadIdx.x] = v4;
}

// ---------------- z_quantized gather, (B,C,H,W) layout ----------------
__global__ __launch_bounds__(256) void zq_fill(const int* __restrict__ idx,
                                               const float* __restrict__ cb,
                                               float* __restrict__ out) {
    int i  = blockIdx.x * 256 + threadIdx.x;
    int hw = i & 1023;
    int c  = (i >> 10) & 255;
    int b  = i >> 18;
    int n  = (b << 10) | hw;
    out[i] = cb[idx[n] * CDIM + c];
}

// ================= fallback path (round-2 fp32 VALU, known-good) =================

__global__ __launch_bounds__(64) void cb_norms(const float* __restrict__ cb,
                                               float* __restrict__ cbn) {
    int k = blockIdx.x;
    int lane = threadIdx.x;
    float4 v = reinterpret_cast<const float4*>(cb + k * CDIM)[lane];
    float s = v.x * v.x + v.y * v.y + v.z * v.z + v.w * v.w;
    #pragma unroll
    for (int off = 32; off > 0; off >>= 1) s += __shfl_down(s, off);
    if (lane == 0) cbn[k] = s;
}

__global__ __launch_bounds__(256) void cb_transpose(const float* __restrict__ cb,
                                                    float* __restrict__ cbt) {
    __shared__ float t[32][33];
    int k0 = (blockIdx.x & 31) * 32;
    int c0 = (blockIdx.x >> 5) * 32;
    int lane = threadIdx.x & 31;
    int row = threadIdx.x >> 5;
    #pragma unroll
    for (int s = 0; s < 4; s++) {
        int r = row + s * 8;
        t[r][lane] = cb[(k0 + r) * CDIM + c0 + lane];
    }
    __syncthreads();
    #pragma unroll
    for (int s = 0; s < 4; s++) {
        int r = row + s * 8;
        cbt[(c0 + r) * K_CODES + k0 + lane] = t[lane][r];
    }
}

__global__ __launch_bounds__(512, 2) void vq_argmin(const float* __restrict__ z,
                                                    const float* __restrict__ cbt,
                                                    const float* __restrict__ cbn,
                                                    int* __restrict__ idx_out) {
    __shared__ float As[64][128];
    __shared__ float Bs[64][256];

    const int tid = threadIdx.x;
    const int tx = tid & 31;
    const int ty = tid >> 5;
    const int rowBase = blockIdx.x * 128;
    const int bb = rowBase >> 10;
    const int hwBase = rowBase & 1023;

    float minv[8];
    int   mini[8];
    #pragma unroll
    for (int i = 0; i < 8; i++) { minv[i] = 3.4e38f; mini[i] = 0; }

    for (int kt = 0; kt < K_CODES; kt += 256) {
        float acc[2][2][4][4];
        #pragma unroll
        for (int a = 0; a < 2; a++)
            #pragma unroll
            for (int b = 0; b < 2; b++)
                #pragma unroll
                for (int i = 0; i < 4; i++)
                    #pragma unroll
                    for (int j = 0; j < 4; j++) acc[a][b][i][j] = 0.f;

        for (int ccb = 0; ccb < CDIM; ccb += 64) {
            #pragma unroll
            for (int l = 0; l < 4; l++) {
                int f = tid + l * 512;
                int r4 = f & 31, c = f >> 5;
                float4 v = *reinterpret_cast<const float4*>(
                    &z[((bb * 256 + ccb + c) << 10) + hwBase + r4 * 4]);
                *reinterpret_cast<float4*>(&As[c][r4 * 4]) = v;
            }
            #pragma unroll
            for (int l = 0; l < 8; l++) {
                int f = tid + l * 512;
                int k4 = f & 63, c = f >> 6;
                float4 v = *reinterpret_cast<const float4*>(
                    &cbt[(ccb + c) * K_CODES + kt + k4 * 4]);
                *reinterpret_cast<float4*>(&Bs[c][k4 * 4]) = v;
            }
            __syncthreads();
            #pragma unroll 4
            for (int c = 0; c < 64; c++) {
                float4 a0 = *reinterpret_cast<const float4*>(&As[c][ty * 4]);
                float4 a1 = *reinterpret_cast<const float4*>(&As[c][64 + ty * 4]);
                float4 b0 = *reinterpret_cast<const float4*>(&Bs[c][tx * 4]);
                float4 b1 = *reinterpret_cast<const float4*>(&Bs[c][128 + tx * 4]);
                float av[2][4] = {{a0.x, a0.y, a0.z, a0.w}, {a1.x, a1.y, a1.z, a1.w}};
                float bw[2][4] = {{b0.x, b0.y, b0.z, b0.w}, {b1.x, b1.y, b1.z, b1.w}};
                #pragma unroll
                for (int ri = 0; ri < 2; ri++)
                    #pragma unroll
                    for (int i = 0; i < 4; i++)
                        #pragma unroll
                        for (int ci = 0; ci < 2; ci++)
                            #pragma unroll
                            for (int j = 0; j < 4; j++)
                                acc[ri][ci][i][j] =
                                    fmaf(av[ri][i], bw[ci][j], acc[ri][ci][i][j]);
            }
            __syncthreads();
        }
        #pragma unroll
        for (int ci = 0; ci < 2; ci++)
            #pragma unroll
            for (int j = 0; j < 4; j++) {
                int code = kt + ci * 128 + tx * 4 + j;
                float nrm = cbn[code];
                #pragma unroll
                for (int ri = 0; ri < 2; ri++)
                    #pragma unroll
                    for (int i = 0; i < 4; i++) {
                        float d = fmaf(-2.f, acc[ri][ci][i][j], nrm);
                        int r = ri * 4 + i;
                        if (d < minv[r]) { minv[r] = d; mini[r] = code; }
                    }
            }
    }

    __syncthreads();
    float (*rv)[32] = reinterpret_cast<float(*)[32]>(&As[0][0]);
    int   (*rix)[32] = reinterpret_cast<int(*)[32]>(&As[32][0]);
    #pragma unroll
    for (int ri = 0; ri < 2; ri++)
        #pragma unroll
        for (int i = 0; i < 4; i++) {
            int row = ri * 64 + ty * 4 + i;
            rv[row][tx] = minv[ri * 4 + i];
            rix[row][tx] = mini[ri * 4 + i];
        }
    __syncthreads();
    if (tid < 128) {
        float bvv = rv[tid][0]; int bii = rix[tid][0];
        #pragma unroll
        for (int t = 1; t < 32; t++) {
            float v = rv[tid][t]; int ii = rix[tid][t];
            if (v < bvv || (v == bvv && ii < bii)) { bvv = v; bii = ii; }
        }
        idx_out[rowBase + tid] = bii;
    }
}

__global__ __launch_bounds__(256) void onehot_fill(const int* __restrict__ idx,
                                                   float* __restrict__ out) {
    int i = blockIdx.x * 256 + threadIdx.x;
    int n  = i >> 8;
    int k4 = (i & 255) << 2;
    int id = idx[n];
    float4 v;
    v.x = (k4     == id) ? 1.f : 0.f;
    v.y = (k4 + 1 == id) ? 1.f : 0.f;
    v.z = (k4 + 2 == id) ? 1.f : 0.f;
    v.w = (k4 + 3 == id) ? 1.f : 0.f;
    reinterpret_cast<float4*>(out)[i] = v;
}

extern "C" void kernel_launch(void* const* d_in, const int* in_sizes, int n_in,
                              void* d_out, int out_size, void* d_ws, size_t ws_size,
                              hipStream_t stream) {
    const float* z  = (const float*)d_in[0];
    const float* cb = (const float*)d_in[1];
    float* out0 = (float*)d_out;
    float* out1 = out0 + (size_t)N_ROWS * K_CODES;

    if (ws_size >= WS_NEED) {
        _Float16* zh  = (_Float16*)((char*)d_ws + WS_ZH);
        _Float16* zl  = (_Float16*)((char*)d_ws + WS_ZL);
        _Float16* cbh = (_Float16*)((char*)d_ws + WS_CBH);
        _Float16* cbl = (_Float16*)((char*)d_ws + WS_CBL);
        float* cbn = (float*)((char*)d_ws + WS_CBN);
        ull* part = (ull*)((char*)d_ws + WS_PART);
        int* idx = (int*)((char*)d_ws + WS_IDX);

        cb_prep<<<K_CODES, 64, 0, stream>>>(cb, cbh, cbl, cbn);
        z_prep<<<2048, 256, 0, stream>>>(z, zh, zl);
        vq_mfma32<<<2048, 256, 0, stream>>>(zh, zl, cbh, cbl, cbn, part);
        onehot_fin<<<N_ROWS, 256, 0, stream>>>(part, idx, out0);
        zq_fill<<<(N_ROWS * CDIM) / 256, 256, 0, stream>>>(idx, cb, out1);
    } else {
        float* cbn = (float*)d_ws;
        int*   idx = (int*)((char*)d_ws + 4096);
        float* cbt = (float*)((char*)d_ws + 4096 + 131072);

        cb_norms<<<K_CODES, 64, 0, stream>>>(cb, cbn);
        cb_transpose<<<256, 256, 0, stream>>>(cb, cbt);
        vq_argmin<<<N_ROWS / 128, 512, 0, stream>>>(z, cbt, cbn, idx);
        onehot_fill<<<(N_ROWS * K_CODES / 4) / 256, 256, 0, stream>>>(idx, out0);
        zq_fill<<<(N_ROWS * CDIM) / 256, 256, 0, stream>>>(idx, cb, out1);
    }
}